// Round 8
// baseline (372.490 us; speedup 1.0000x reference)
//
#include <hip/hip_runtime.h>
#include <hip/hip_bf16.h>

typedef _Float16 f16;
typedef _Float16 f16x8 __attribute__((ext_vector_type(8)));
typedef _Float16 f16x4 __attribute__((ext_vector_type(4)));
typedef float f32x4 __attribute__((ext_vector_type(4)));

#define MFMA_F16(a, b, c) __builtin_amdgcn_mfma_f32_16x16x32_f16((a), (b), (c), 0, 0, 0)

static constexpr int S_TOK = 2048;
static constexpr int N_HEAD = 16;
static constexpr int N_KV = 4;
static constexpr int HD = 64;
// softmax uses exp2: exp(s*0.125) == exp2(s*0.125*log2(e))
static constexpr float SCL2E = 0.125f * 1.4426950408889634f;

// ws element offsets (f16 units)
static constexpr size_t OFF_X16 = 0;                      // 4,194,304
static constexpr size_t OFF_QW = 4194304;                 // 1,048,576
static constexpr size_t OFF_KW = OFF_QW + 1048576;        // 262,144
static constexpr size_t OFF_VW = OFF_KW + 262144;         // 262,144
static constexpr size_t OFF_OW = OFF_VW + 262144;         // 1,048,576
static constexpr size_t OFF_QS = OFF_OW + 1048576;        // 4,194,304
static constexpr size_t OFF_KS = OFF_QS + 4194304;        // 1,048,576
static constexpr size_t OFF_VS = OFF_KS + 1048576;        // 1,048,576
static constexpr size_t OFF_OS = OFF_VS + 1048576;        // 4,194,304
static constexpr size_t CVT_TOTAL = OFF_OW + 1048576;     // 6,815,744 elems
// lsum partials ALIAS the x16 region (dead after k_qkv): [head][row][half] f32
// 32*2048*2 floats = 512 KB <= x16's 8 MB.

// ---------------------------------------------------------------------------
// Kernel 0: fp32 -> f16 conversion of x and all four weight matrices.
// ---------------------------------------------------------------------------
__global__ __launch_bounds__(256) void k_cvt(
    const float* __restrict__ x, const float* __restrict__ qw,
    const float* __restrict__ kw, const float* __restrict__ vw,
    const float* __restrict__ ow, f16* __restrict__ dst) {
  size_t i = ((size_t)blockIdx.x * 256 + threadIdx.x) * 4;
  if (i >= CVT_TOTAL) return;
  const float* src;
  size_t off;
  if (i < OFF_QW) { src = x; off = i; }
  else if (i < OFF_KW) { src = qw; off = i - OFF_QW; }
  else if (i < OFF_VW) { src = kw; off = i - OFF_KW; }
  else if (i < OFF_OW) { src = vw; off = i - OFF_VW; }
  else { src = ow; off = i - OFF_OW; }
  float4 v = *(const float4*)(src + off);
  *(f16x4*)(dst + i) = f16x4{(f16)v.x, (f16)v.y, (f16)v.z, (f16)v.w};
}

// ---------------------------------------------------------------------------
// Kernel 1: fused QKV projection + bias + partial RoPE (f16 inputs).
//   q_ws: [b][h][s][hd], k_ws: [b][kv][s][hd], v_ws TRANSPOSED: [b][kv][hd][s]
// ---------------------------------------------------------------------------
__global__ __launch_bounds__(256) void k_qkv(
    const f16* __restrict__ x, const float* __restrict__ cosp,
    const float* __restrict__ sinp, const f16* __restrict__ q_w,
    const float* __restrict__ q_b, const f16* __restrict__ k_w,
    const f16* __restrict__ v_w, const float* __restrict__ v_b,
    f16* __restrict__ q_ws, f16* __restrict__ k_ws, f16* __restrict__ v_ws) {
  __shared__ f16 wb[64][72];
  const int tid = threadIdx.x;
  const int wave = tid >> 6, lane = tid & 63;
  const int l16 = lane & 15, g = lane >> 4;
  const int m0 = blockIdx.x * 64;
  const int n0 = blockIdx.y * 64;

  const f16* W;
  int ldW, nloc, mode;  // mode 0=q 1=k 2=v
  if (n0 < 1024) { W = q_w; ldW = 1024; nloc = n0; mode = 0; }
  else if (n0 < 1280) { W = k_w; ldW = 256; nloc = n0 - 1024; mode = 1; }
  else { W = v_w; ldW = 256; nloc = n0 - 1280; mode = 2; }

  f32x4 acc[4] = {};
  const int kk = (tid >> 4) * 4;  // k within tile
  const int nn = (tid & 15) * 4;  // n within tile

  for (int k0 = 0; k0 < 1024; k0 += 64) {
    const f16* wp = W + (size_t)(k0 + kk) * ldW + nloc + nn;
    f16x4 w0 = *(const f16x4*)(wp);
    f16x4 w1 = *(const f16x4*)(wp + ldW);
    f16x4 w2 = *(const f16x4*)(wp + 2 * ldW);
    f16x4 w3 = *(const f16x4*)(wp + 3 * ldW);
    __syncthreads();
    *(f16x4*)&wb[nn + 0][kk] = f16x4{w0[0], w1[0], w2[0], w3[0]};
    *(f16x4*)&wb[nn + 1][kk] = f16x4{w0[1], w1[1], w2[1], w3[1]};
    *(f16x4*)&wb[nn + 2][kk] = f16x4{w0[2], w1[2], w2[2], w3[2]};
    *(f16x4*)&wb[nn + 3][kk] = f16x4{w0[3], w1[3], w2[3], w3[3]};
    __syncthreads();
    const f16* xp = x + (size_t)(m0 + wave * 16 + l16) * 1024 + k0 + g * 8;
#pragma unroll
    for (int ks = 0; ks < 2; ++ks) {
      f16x8 af = *(const f16x8*)(xp + ks * 32);
#pragma unroll
      for (int n = 0; n < 4; ++n) {
        f16x8 bf = *(const f16x8*)&wb[n * 16 + l16][ks * 32 + g * 8];
        acc[n] = MFMA_F16(af, bf, acc[n]);
      }
    }
  }

  if (mode == 0) {
#pragma unroll
    for (int n = 0; n < 4; ++n) {
      float bsc = q_b[n0 + n * 16 + l16];
#pragma unroll
      for (int r = 0; r < 4; ++r) acc[n][r] += bsc;
    }
  } else if (mode == 2) {
#pragma unroll
    for (int n = 0; n < 4; ++n) {
      float bsc = v_b[nloc + n * 16 + l16];
#pragma unroll
      for (int r = 0; r < 4; ++r) acc[n][r] += bsc;
    }
  }
  if (mode < 2) {  // RoPE: frag0 cols pair with frag1 cols (d, d+16)
#pragma unroll
    for (int r = 0; r < 4; ++r) {
      int row = m0 + wave * 16 + g * 4 + r;
      int bb = row >> 11, ss = row & 2047;
      float c = cosp[((size_t)bb * S_TOK + ss) * 32 + l16];
      float sn = sinp[((size_t)bb * S_TOK + ss) * 32 + l16];
      float v0 = acc[0][r], v1 = acc[1][r];
      acc[0][r] = v0 * c - v1 * sn;
      acc[1][r] = v1 * c + v0 * sn;
    }
  }
#pragma unroll
  for (int n = 0; n < 4; ++n) {
#pragma unroll
    for (int r = 0; r < 4; ++r) {
      int row = m0 + wave * 16 + g * 4 + r;
      int bb = row >> 11, ss = row & 2047;
      f16 val = (f16)acc[n][r];
      if (mode == 0) {
        int col = n0 + n * 16 + l16;
        int h = col >> 6, hd = col & 63;
        q_ws[(((size_t)bb * N_HEAD + h) * S_TOK + ss) * HD + hd] = val;
      } else {
        int col = nloc + n * 16 + l16;
        int kh = col >> 6, hd = col & 63;
        if (mode == 1)
          k_ws[(((size_t)bb * N_KV + kh) * S_TOK + ss) * HD + hd] = val;
        else
          v_ws[(((size_t)bb * N_KV + kh) * HD + hd) * S_TOK + ss] = val;
      }
    }
  }
}

// ---------------------------------------------------------------------------
// Kernel 2a: softmax row-sums (pass A split out for occupancy).
// Swapped QK^T (mfma(K,Q)): lane's 4 accumulator regs are 4 keys of q-col
// l16 -> row-sum = 4 adds + 2 shuffles. 16 q-rows/wave, half key-range/wave.
// No LDS, ~50 VGPR -> 8 waves/SIMD; grid 2048 blocks fills the chip 2x.
// lsum_ws[head][row][half] f32 (aliases dead x16 region).
// ---------------------------------------------------------------------------
__global__ __launch_bounds__(256) void k_lsum(
    const f16* __restrict__ q_ws, const f16* __restrict__ k_ws,
    float* __restrict__ lsum_ws) {
  const int tid = threadIdx.x;
  const int wave = tid >> 6, lane = tid & 63;
  const int l16 = lane & 15, g = lane >> 4;
  // XCD decode: bid&7 -> (b,kvh); per combo: 4 heads x 32 qt64 x 2 halves.
  const int bid = blockIdx.x;
  const int combo = bid & 7, local = bid >> 3;
  const int b = combo >> 2, kvh = combo & 3;
  const int hg = local >> 6;           // head within group (0..3)
  const int rem = local & 63;
  const int qt = rem >> 1, half = rem & 1;
  const int head = b * N_HEAD + kvh * 4 + hg;
  const int qrow0 = qt * 64 + wave * 16;

  const f16* qb = q_ws + ((size_t)head * S_TOK + qrow0) * HD;
  const f16* kb = k_ws + (size_t)(b * N_KV + kvh) * S_TOK * HD;

  f16x8 qf[2];  // B-operand: col = q = l16, k = hd
  qf[0] = *(const f16x8*)(qb + l16 * HD + g * 8);
  qf[1] = *(const f16x8*)(qb + l16 * HD + 32 + g * 8);

  float lsum = 0.0f;
  const int kt0 = half * 16, kt1 = kt0 + 16;
  for (int kt = kt0; kt < kt1; ++kt) {
    const f16* kp = kb + (size_t)kt * 64 * HD;
#pragma unroll
    for (int n = 0; n < 4; ++n) {
      f16x8 k0f = *(const f16x8*)(kp + (n * 16 + l16) * HD + g * 8);
      f16x8 k1f = *(const f16x8*)(kp + (n * 16 + l16) * HD + 32 + g * 8);
      f32x4 s = {};
      s = MFMA_F16(k0f, qf[0], s);
      s = MFMA_F16(k1f, qf[1], s);
      lsum += exp2f(s[0] * SCL2E) + exp2f(s[1] * SCL2E) +
              exp2f(s[2] * SCL2E) + exp2f(s[3] * SCL2E);
    }
  }
  lsum += __shfl_xor(lsum, 16, 64);
  lsum += __shfl_xor(lsum, 32, 64);
  if (lane < 16)  // g==0, one writer per q-row
    lsum_ws[((size_t)head * S_TOK + qrow0 + l16) * 2 + half] = lsum;
}

// ---------------------------------------------------------------------------
// Kernel 2b: attention pass B — EXACT R6 structure (best: 305 µs) minus the
// inline pass A; linv read from lsum_ws. NT stores restored (R7: plain cost
// +31). Split-K wave pairs, f16 LDS roundtrip for P, coalesced NT stores,
// pair O combine. XCD decode kept.
// ---------------------------------------------------------------------------
__global__ __launch_bounds__(256, 3) void k_attn(
    const f16* __restrict__ q_ws, const f16* __restrict__ k_ws,
    const f16* __restrict__ v_ws, const float* __restrict__ lsum_ws,
    f16* __restrict__ o_ws, float* __restrict__ probs) {
  __shared__ f16 plds_all[4][32][72];
  __shared__ float osum[2][32][68];
  const int tid = threadIdx.x;
  const int wave = tid >> 6, lane = tid & 63;
  const int pairi = wave >> 1, half = wave & 1;
  const int l16 = lane & 15, g = lane >> 4;
  const int bid = blockIdx.x;
  const int combo = bid & 7, local = bid >> 3;
  const int b = combo >> 2, kvh = combo & 3;
  const int h = kvh * 4 + (local >> 5);
  const int rt = local & 31;
  const int head = b * N_HEAD + h;
  const int qrow0 = rt * 64 + pairi * 32;

  const f16* qb = q_ws + ((size_t)head * S_TOK + qrow0) * HD;
  const f16* kb = k_ws + (size_t)(b * N_KV + kvh) * S_TOK * HD;
  const f16* vb = v_ws + (size_t)(b * N_KV + kvh) * HD * S_TOK;  // [hd][s]
  float* pout = probs + (size_t)head * S_TOK * S_TOK + (size_t)qrow0 * S_TOK;
  f16(*plds)[72] = plds_all[wave];

  f16x8 qf[2][2];
#pragma unroll
  for (int mf = 0; mf < 2; ++mf)
#pragma unroll
    for (int ks = 0; ks < 2; ++ks)
      qf[mf][ks] = *(const f16x8*)(qb + (mf * 16 + l16) * HD + ks * 32 + g * 8);

  // linv from pass A partials (L2-hot; lanes of same g broadcast-read)
  float linv[2][4];
#pragma unroll
  for (int mf = 0; mf < 2; ++mf)
#pragma unroll
    for (int r = 0; r < 4; ++r) {
      size_t base = ((size_t)head * S_TOK + qrow0 + mf * 16 + g * 4 + r) * 2;
      linv[mf][r] = 1.0f / (lsum_ws[base] + lsum_ws[base + 1]);
    }

  const int kt0 = half * 16, kt1 = kt0 + 16;

  // ---- probs write + partial PV ----
  f32x4 oacc[2][4] = {};
  const int orow = lane >> 4, oq = lane & 15;
  for (int kt = kt0; kt < kt1; ++kt) {
    const f16* kp = kb + (size_t)kt * 64 * HD;
#pragma unroll
    for (int n = 0; n < 4; ++n) {
      f16x8 k0f = *(const f16x8*)(kp + (n * 16 + l16) * HD + g * 8);
      f16x8 k1f = *(const f16x8*)(kp + (n * 16 + l16) * HD + 32 + g * 8);
#pragma unroll
      for (int mf = 0; mf < 2; ++mf) {
        f32x4 s = {};
        s = MFMA_F16(qf[mf][0], k0f, s);
        s = MFMA_F16(qf[mf][1], k1f, s);
#pragma unroll
        for (int r = 0; r < 4; ++r) {
          float p = exp2f(s[r] * SCL2E) * linv[mf][r];
          plds[mf * 16 + g * 4 + r][n * 16 + l16] = (f16)p;
        }
      }
    }
    asm volatile("s_waitcnt lgkmcnt(0)" ::: "memory");  // intra-wave LDS vis
    f16x8 pa[2][2];
#pragma unroll
    for (int mf = 0; mf < 2; ++mf)
#pragma unroll
      for (int ks = 0; ks < 2; ++ks)
        pa[mf][ks] = *(const f16x8*)&plds[mf * 16 + l16][ks * 32 + g * 8];
#pragma unroll
    for (int nh = 0; nh < 4; ++nh) {
      const f16* vp = vb + (size_t)(nh * 16 + l16) * S_TOK + kt * 64;
      f16x8 v0f = *(const f16x8*)(vp + g * 8);
      f16x8 v1f = *(const f16x8*)(vp + 32 + g * 8);
#pragma unroll
      for (int mf = 0; mf < 2; ++mf) {
        oacc[mf][nh] = MFMA_F16(pa[mf][0], v0f, oacc[mf][nh]);
        oacc[mf][nh] = MFMA_F16(pa[mf][1], v1f, oacc[mf][nh]);
      }
    }
    // nontemporal coalesced probs write: each inst covers 4 full 256B rows
#pragma unroll
    for (int it = 0; it < 8; ++it) {
      int rr = it * 4 + orow;
      f16x4 pv = *(const f16x4*)&plds[rr][oq * 4];
      f32x4 ov = {(float)pv[0], (float)pv[1], (float)pv[2], (float)pv[3]};
      __builtin_nontemporal_store(
          ov, (f32x4*)(pout + (size_t)rr * S_TOK + kt * 64 + oq * 4));
    }
    asm volatile("" ::: "memory");  // keep next iter's LDS writes after reads
  }

  // ---- pair O combine ----
  if (half == 1) {
#pragma unroll
    for (int mf = 0; mf < 2; ++mf)
#pragma unroll
      for (int nh = 0; nh < 4; ++nh)
#pragma unroll
        for (int r = 0; r < 4; ++r)
          osum[pairi][mf * 16 + g * 4 + r][nh * 16 + l16] = oacc[mf][nh][r];
  }
  __syncthreads();
  if (half == 0) {
#pragma unroll
    for (int mf = 0; mf < 2; ++mf)
#pragma unroll
      for (int nh = 0; nh < 4; ++nh)
#pragma unroll
        for (int r = 0; r < 4; ++r) {
          int row = mf * 16 + g * 4 + r;
          float v = oacc[mf][nh][r] + osum[pairi][row][nh * 16 + l16];
          o_ws[((size_t)b * S_TOK + qrow0 + row) * 1024 + h * HD + nh * 16 +
               l16] = (f16)v;
        }
  }
}

// ---------------------------------------------------------------------------
// Kernel 3: O projection (f16 weights). o_ws @ o_w + o_b -> d_out fp32
// ---------------------------------------------------------------------------
__global__ __launch_bounds__(256) void k_oproj(
    const f16* __restrict__ a, const f16* __restrict__ o_w,
    const float* __restrict__ o_b, float* __restrict__ out) {
  __shared__ f16 wb[64][72];
  const int tid = threadIdx.x;
  const int wave = tid >> 6, lane = tid & 63;
  const int l16 = lane & 15, g = lane >> 4;
  const int m0 = blockIdx.x * 64, n0 = blockIdx.y * 64;
  f32x4 acc[4] = {};
  const int kk = (tid >> 4) * 4, nn = (tid & 15) * 4;
  for (int k0 = 0; k0 < 1024; k0 += 64) {
    const f16* wp = o_w + (size_t)(k0 + kk) * 1024 + n0 + nn;
    f16x4 w0 = *(const f16x4*)(wp);
    f16x4 w1 = *(const f16x4*)(wp + 1024);
    f16x4 w2 = *(const f16x4*)(wp + 2048);
    f16x4 w3 = *(const f16x4*)(wp + 3072);
    __syncthreads();
    *(f16x4*)&wb[nn + 0][kk] = f16x4{w0[0], w1[0], w2[0], w3[0]};
    *(f16x4*)&wb[nn + 1][kk] = f16x4{w0[1], w1[1], w2[1], w3[1]};
    *(f16x4*)&wb[nn + 2][kk] = f16x4{w0[2], w1[2], w2[2], w3[2]};
    *(f16x4*)&wb[nn + 3][kk] = f16x4{w0[3], w1[3], w2[3], w3[3]};
    __syncthreads();
    const f16* ap = a + (size_t)(m0 + wave * 16 + l16) * 1024 + k0 + g * 8;
#pragma unroll
    for (int ks = 0; ks < 2; ++ks) {
      f16x8 af = *(const f16x8*)(ap + ks * 32);
#pragma unroll
      for (int n = 0; n < 4; ++n) {
        f16x8 bf = *(const f16x8*)&wb[n * 16 + l16][ks * 32 + g * 8];
        acc[n] = MFMA_F16(af, bf, acc[n]);
      }
    }
  }
#pragma unroll
  for (int n = 0; n < 4; ++n) {
    float bsc = o_b[n0 + n * 16 + l16];
#pragma unroll
    for (int r = 0; r < 4; ++r) {
      int row = m0 + wave * 16 + g * 4 + r;
      out[(size_t)row * 1024 + n0 + n * 16 + l16] = acc[n][r] + bsc;
    }
  }
}

extern "C" void kernel_launch(void* const* d_in, const int* in_sizes, int n_in,
                              void* d_out, int out_size, void* d_ws,
                              size_t ws_size, hipStream_t stream) {
  (void)in_sizes; (void)n_in; (void)out_size; (void)ws_size;
  const float* x    = (const float*)d_in[0];
  const float* cosp = (const float*)d_in[1];
  const float* sinp = (const float*)d_in[2];
  const float* q_w  = (const float*)d_in[3];
  const float* q_b  = (const float*)d_in[4];
  const float* k_w  = (const float*)d_in[5];
  const float* v_w  = (const float*)d_in[6];
  const float* v_b  = (const float*)d_in[7];
  const float* o_w  = (const float*)d_in[8];
  const float* o_b  = (const float*)d_in[9];

  f16* ws = (f16*)d_ws;
  f16* x16  = ws + OFF_X16;
  f16* qw16 = ws + OFF_QW;
  f16* kw16 = ws + OFF_KW;
  f16* vw16 = ws + OFF_VW;
  f16* ow16 = ws + OFF_OW;
  f16* q_ws = ws + OFF_QS;
  f16* k_ws = ws + OFF_KS;
  f16* v_ws = ws + OFF_VS;
  f16* o_ws = ws + OFF_OS;
  // lsum partials alias x16 (dead after k_qkv): 512 KB
  float* lsum_ws = (float*)(ws + OFF_X16);
  float* out = (float*)d_out;          // attn_output [0, 4194304)
  float* probs = out + 4194304;        // attn_weights

  k_cvt<<<dim3((CVT_TOTAL / 4 + 255) / 256), 256, 0, stream>>>(
      x, q_w, k_w, v_w, o_w, ws);
  k_qkv<<<dim3(64, 24), 256, 0, stream>>>(x16, cosp, sinp, qw16, q_b, kw16,
                                          vw16, v_b, q_ws, k_ws, v_ws);
  k_lsum<<<dim3(2048), 256, 0, stream>>>(q_ws, k_ws, lsum_ws);
  k_attn<<<dim3(1024), 256, 0, stream>>>(q_ws, k_ws, v_ws, lsum_ws, o_ws,
                                         probs);
  k_oproj<<<dim3(64, 16), 256, 0, stream>>>(o_ws, ow16, o_b, out);
}

// Round 9
// 301.685 us; speedup vs baseline: 1.2347x; 1.2347x over previous
//
#include <hip/hip_runtime.h>
#include <hip/hip_bf16.h>

typedef _Float16 f16;
typedef _Float16 f16x8 __attribute__((ext_vector_type(8)));
typedef _Float16 f16x4 __attribute__((ext_vector_type(4)));
typedef float f32x4 __attribute__((ext_vector_type(4)));

#define MFMA_F16(a, b, c) __builtin_amdgcn_mfma_f32_16x16x32_f16((a), (b), (c), 0, 0, 0)

static constexpr int S_TOK = 2048;
static constexpr int N_HEAD = 16;
static constexpr int N_KV = 4;
static constexpr int HD = 64;
// softmax uses exp2: exp(s*0.125) == exp2(s*0.125*log2(e))
static constexpr float SCL2E = 0.125f * 1.4426950408889634f;

// ws element offsets (f16 units)
static constexpr size_t OFF_X16 = 0;                      // 4,194,304
static constexpr size_t OFF_QW = 4194304;                 // 1,048,576
static constexpr size_t OFF_KW = OFF_QW + 1048576;        // 262,144
static constexpr size_t OFF_VW = OFF_KW + 262144;         // 262,144
static constexpr size_t OFF_OW = OFF_VW + 262144;         // 1,048,576
static constexpr size_t OFF_QS = OFF_OW + 1048576;        // 4,194,304
static constexpr size_t OFF_KS = OFF_QS + 4194304;        // 1,048,576
static constexpr size_t OFF_VS = OFF_KS + 1048576;        // 1,048,576
static constexpr size_t OFF_OS = OFF_VS + 1048576;        // 4,194,304
static constexpr size_t CVT_TOTAL = OFF_OW + 1048576;     // 6,815,744 elems

// ---------------------------------------------------------------------------
// Kernel 0: fp32 -> f16 conversion of x and all four weight matrices.
// ---------------------------------------------------------------------------
__global__ __launch_bounds__(256) void k_cvt(
    const float* __restrict__ x, const float* __restrict__ qw,
    const float* __restrict__ kw, const float* __restrict__ vw,
    const float* __restrict__ ow, f16* __restrict__ dst) {
  size_t i = ((size_t)blockIdx.x * 256 + threadIdx.x) * 4;
  if (i >= CVT_TOTAL) return;
  const float* src;
  size_t off;
  if (i < OFF_QW) { src = x; off = i; }
  else if (i < OFF_KW) { src = qw; off = i - OFF_QW; }
  else if (i < OFF_VW) { src = kw; off = i - OFF_KW; }
  else if (i < OFF_OW) { src = vw; off = i - OFF_VW; }
  else { src = ow; off = i - OFF_OW; }
  float4 v = *(const float4*)(src + off);
  *(f16x4*)(dst + i) = f16x4{(f16)v.x, (f16)v.y, (f16)v.z, (f16)v.w};
}

// ---------------------------------------------------------------------------
// Kernel 1: fused QKV projection, 128x128 tile (4 waves as 2x2, 64x64 each,
// BK=64, 32 MFMA/wave/K-step — 4x the amortization of the old 64^2 tile).
// Epilogue: bias + partial RoPE + scatter to q_ws/k_ws/v_ws (same math as
// R6's validated kernel; K-summation order identical -> bitwise-same output).
// grid (32, 12): n-tiles 0-7 q, 8-9 k, 10-11 v; each wave's 64-col block is
// head-aligned (HD=64) so RoPE pairs are acc[mi][0]<->acc[mi][1].
// ---------------------------------------------------------------------------
__global__ __launch_bounds__(256) void k_qkv(
    const f16* __restrict__ x, const float* __restrict__ cosp,
    const float* __restrict__ sinp, const f16* __restrict__ q_w,
    const float* __restrict__ q_b, const f16* __restrict__ k_w,
    const f16* __restrict__ v_w, const float* __restrict__ v_b,
    f16* __restrict__ q_ws, f16* __restrict__ k_ws, f16* __restrict__ v_ws) {
  __shared__ f16 at[128][72];   // A rows x k   (+8 pad)
  __shared__ f16 bt[128][72];   // B cols(n) x k
  const int tid = threadIdx.x;
  const int wave = tid >> 6, lane = tid & 63;
  const int l16 = lane & 15, g = lane >> 4;
  const int wm = wave >> 1, wn = wave & 1;
  const int m0 = blockIdx.x * 128;
  const int n0 = blockIdx.y * 128;

  const f16* W;
  int ldW, nbase;  // nbase = col offset within the selected weight matrix
  if (n0 < 1024) { W = q_w; ldW = 1024; nbase = n0; }
  else if (n0 < 1280) { W = k_w; ldW = 256; nbase = n0 - 1024; }
  else { W = v_w; ldW = 256; nbase = n0 - 1280; }

  f32x4 acc[4][4] = {};
  const int arow = tid >> 3, asub = tid & 7;             // A: 32 rows/iter
  const int bkr = (tid >> 4) * 4, bnc = (tid & 15) * 4;  // B: 4k x 4n chunks

  for (int k0 = 0; k0 < 1024; k0 += 64) {
    f16x8 av[4];
#pragma unroll
    for (int it = 0; it < 4; ++it)
      av[it] = *(const f16x8*)(x + (size_t)(m0 + it * 32 + arow) * 1024 + k0 +
                               asub * 8);
    f16x4 bv[2][4];
#pragma unroll
    for (int it = 0; it < 2; ++it)
#pragma unroll
      for (int kk = 0; kk < 4; ++kk)
        bv[it][kk] = *(const f16x4*)(W + (size_t)(k0 + bkr + kk) * ldW + nbase +
                                     it * 64 + bnc);
    __syncthreads();
#pragma unroll
    for (int it = 0; it < 4; ++it)
      *(f16x8*)&at[it * 32 + arow][asub * 8] = av[it];
#pragma unroll
    for (int it = 0; it < 2; ++it)
#pragma unroll
      for (int i = 0; i < 4; ++i)
        *(f16x4*)&bt[it * 64 + bnc + i][bkr] =
            f16x4{bv[it][0][i], bv[it][1][i], bv[it][2][i], bv[it][3][i]};
    __syncthreads();
#pragma unroll
    for (int ks = 0; ks < 2; ++ks) {
      f16x8 af[4], bf[4];
#pragma unroll
      for (int mi = 0; mi < 4; ++mi)
        af[mi] = *(const f16x8*)&at[wm * 64 + mi * 16 + l16][ks * 32 + g * 8];
#pragma unroll
      for (int ni = 0; ni < 4; ++ni)
        bf[ni] = *(const f16x8*)&bt[wn * 64 + ni * 16 + l16][ks * 32 + g * 8];
#pragma unroll
      for (int mi = 0; mi < 4; ++mi)
#pragma unroll
        for (int ni = 0; ni < 4; ++ni)
          acc[mi][ni] = MFMA_F16(af[mi], bf[ni], acc[mi][ni]);
    }
  }

  // ---- epilogue: mode per wave (64-col block is head-aligned) ----
  const int gc0 = n0 + wn * 64;
  int mode, nloc;
  if (gc0 < 1024) { mode = 0; nloc = gc0; }
  else if (gc0 < 1280) { mode = 1; nloc = gc0 - 1024; }
  else { mode = 2; nloc = gc0 - 1280; }

  if (mode == 0) {
#pragma unroll
    for (int ni = 0; ni < 4; ++ni) {
      float bsc = q_b[gc0 + ni * 16 + l16];
#pragma unroll
      for (int mi = 0; mi < 4; ++mi)
#pragma unroll
        for (int r = 0; r < 4; ++r) acc[mi][ni][r] += bsc;
    }
  } else if (mode == 2) {
#pragma unroll
    for (int ni = 0; ni < 4; ++ni) {
      float bsc = v_b[nloc + ni * 16 + l16];
#pragma unroll
      for (int mi = 0; mi < 4; ++mi)
#pragma unroll
        for (int r = 0; r < 4; ++r) acc[mi][ni][r] += bsc;
    }
  }
  if (mode < 2) {  // RoPE: hd<16 (ni=0) pairs hd+16 (ni=1); cos duplicated
#pragma unroll
    for (int mi = 0; mi < 4; ++mi)
#pragma unroll
      for (int r = 0; r < 4; ++r) {
        int row = m0 + wm * 64 + mi * 16 + g * 4 + r;
        int bb = row >> 11, ss = row & 2047;
        float c = cosp[((size_t)bb * S_TOK + ss) * 32 + l16];
        float sn = sinp[((size_t)bb * S_TOK + ss) * 32 + l16];
        float v0 = acc[mi][0][r], v1 = acc[mi][1][r];
        acc[mi][0][r] = v0 * c - v1 * sn;
        acc[mi][1][r] = v1 * c + v0 * sn;
      }
  }
#pragma unroll
  for (int mi = 0; mi < 4; ++mi)
#pragma unroll
    for (int ni = 0; ni < 4; ++ni)
#pragma unroll
      for (int r = 0; r < 4; ++r) {
        int row = m0 + wm * 64 + mi * 16 + g * 4 + r;
        int bb = row >> 11, ss = row & 2047;
        f16 val = (f16)acc[mi][ni][r];
        if (mode == 0) {
          int col = gc0 + ni * 16 + l16;
          int h = col >> 6, hd = col & 63;
          q_ws[(((size_t)bb * N_HEAD + h) * S_TOK + ss) * HD + hd] = val;
        } else {
          int col = nloc + ni * 16 + l16;
          int kh = col >> 6, hd = col & 63;
          if (mode == 1)
            k_ws[(((size_t)bb * N_KV + kh) * S_TOK + ss) * HD + hd] = val;
          else
            v_ws[(((size_t)bb * N_KV + kh) * HD + hd) * S_TOK + ss] = val;
        }
      }
}

// ---------------------------------------------------------------------------
// Kernel 2: attention — EXACT R6 kernel (305 µs best): split-K wave pairs,
// inline pass A, f16 LDS roundtrip for P, 256B-coalesced NT stores, pair O
// combine, XCD decode. DO NOT TOUCH (R3/R4/R5/R8 all regressed).
// ---------------------------------------------------------------------------
__global__ __launch_bounds__(256, 3) void k_attn(
    const f16* __restrict__ q_ws, const f16* __restrict__ k_ws,
    const f16* __restrict__ v_ws, f16* __restrict__ o_ws,
    float* __restrict__ probs) {
  __shared__ f16 plds_all[4][32][72];
  __shared__ float lpart[2][2][32];
  __shared__ float osum[2][32][68];
  const int tid = threadIdx.x;
  const int wave = tid >> 6, lane = tid & 63;
  const int pairi = wave >> 1, half = wave & 1;
  const int l16 = lane & 15, g = lane >> 4;
  const int bid = blockIdx.x;
  const int combo = bid & 7, local = bid >> 3;
  const int b = combo >> 2, kvh = combo & 3;
  const int h = kvh * 4 + (local >> 5);
  const int rt = local & 31;
  const int head = b * N_HEAD + h;
  const int qrow0 = rt * 64 + pairi * 32;

  const f16* qb = q_ws + ((size_t)head * S_TOK + qrow0) * HD;
  const f16* kb = k_ws + (size_t)(b * N_KV + kvh) * S_TOK * HD;
  const f16* vb = v_ws + (size_t)(b * N_KV + kvh) * HD * S_TOK;  // [hd][s]
  float* pout = probs + (size_t)head * S_TOK * S_TOK + (size_t)qrow0 * S_TOK;
  f16(*plds)[72] = plds_all[wave];

  f16x8 qf[2][2];
#pragma unroll
  for (int mf = 0; mf < 2; ++mf)
#pragma unroll
    for (int ks = 0; ks < 2; ++ks)
      qf[mf][ks] = *(const f16x8*)(qb + (mf * 16 + l16) * HD + ks * 32 + g * 8);

  const int kt0 = half * 16, kt1 = kt0 + 16;

  // ---- pass A: partial row sums of exp over this wave's key half ----
  float lsum[2][4] = {};
  for (int kt = kt0; kt < kt1; ++kt) {
    const f16* kp = kb + (size_t)kt * 64 * HD;
#pragma unroll
    for (int n = 0; n < 4; ++n) {
      f16x8 k0f = *(const f16x8*)(kp + (n * 16 + l16) * HD + g * 8);
      f16x8 k1f = *(const f16x8*)(kp + (n * 16 + l16) * HD + 32 + g * 8);
#pragma unroll
      for (int mf = 0; mf < 2; ++mf) {
        f32x4 s = {};
        s = MFMA_F16(qf[mf][0], k0f, s);
        s = MFMA_F16(qf[mf][1], k1f, s);
#pragma unroll
        for (int r = 0; r < 4; ++r) lsum[mf][r] += exp2f(s[r] * SCL2E);
      }
    }
  }
#pragma unroll
  for (int mf = 0; mf < 2; ++mf)
#pragma unroll
    for (int r = 0; r < 4; ++r) {
      float v = lsum[mf][r];
      v += __shfl_xor(v, 1, 64);
      v += __shfl_xor(v, 2, 64);
      v += __shfl_xor(v, 4, 64);
      v += __shfl_xor(v, 8, 64);
      lsum[mf][r] = v;  // half-range row sum, replicated across 16-lane group
    }
  if (l16 == 0) {
#pragma unroll
    for (int mf = 0; mf < 2; ++mf)
#pragma unroll
      for (int r = 0; r < 4; ++r)
        lpart[pairi][half][mf * 16 + g * 4 + r] = lsum[mf][r];
  }
  __syncthreads();
  float linv[2][4];
#pragma unroll
  for (int mf = 0; mf < 2; ++mf)
#pragma unroll
    for (int r = 0; r < 4; ++r) {
      int row = mf * 16 + g * 4 + r;
      linv[mf][r] = 1.0f / (lpart[pairi][0][row] + lpart[pairi][1][row]);
    }

  // ---- pass B: probs write + partial PV ----
  f32x4 oacc[2][4] = {};
  const int orow = lane >> 4, oq = lane & 15;
  for (int kt = kt0; kt < kt1; ++kt) {
    const f16* kp = kb + (size_t)kt * 64 * HD;
#pragma unroll
    for (int n = 0; n < 4; ++n) {
      f16x8 k0f = *(const f16x8*)(kp + (n * 16 + l16) * HD + g * 8);
      f16x8 k1f = *(const f16x8*)(kp + (n * 16 + l16) * HD + 32 + g * 8);
#pragma unroll
      for (int mf = 0; mf < 2; ++mf) {
        f32x4 s = {};
        s = MFMA_F16(qf[mf][0], k0f, s);
        s = MFMA_F16(qf[mf][1], k1f, s);
#pragma unroll
        for (int r = 0; r < 4; ++r) {
          float p = exp2f(s[r] * SCL2E) * linv[mf][r];
          plds[mf * 16 + g * 4 + r][n * 16 + l16] = (f16)p;
        }
      }
    }
    asm volatile("s_waitcnt lgkmcnt(0)" ::: "memory");  // intra-wave LDS vis
    f16x8 pa[2][2];
#pragma unroll
    for (int mf = 0; mf < 2; ++mf)
#pragma unroll
      for (int ks = 0; ks < 2; ++ks)
        pa[mf][ks] = *(const f16x8*)&plds[mf * 16 + l16][ks * 32 + g * 8];
#pragma unroll
    for (int nh = 0; nh < 4; ++nh) {
      const f16* vp = vb + (size_t)(nh * 16 + l16) * S_TOK + kt * 64;
      f16x8 v0f = *(const f16x8*)(vp + g * 8);
      f16x8 v1f = *(const f16x8*)(vp + 32 + g * 8);
#pragma unroll
      for (int mf = 0; mf < 2; ++mf) {
        oacc[mf][nh] = MFMA_F16(pa[mf][0], v0f, oacc[mf][nh]);
        oacc[mf][nh] = MFMA_F16(pa[mf][1], v1f, oacc[mf][nh]);
      }
    }
    // nontemporal coalesced probs write: each inst covers 4 full 256B rows
#pragma unroll
    for (int it = 0; it < 8; ++it) {
      int rr = it * 4 + orow;
      f16x4 pv = *(const f16x4*)&plds[rr][oq * 4];
      f32x4 ov = {(float)pv[0], (float)pv[1], (float)pv[2], (float)pv[3]};
      __builtin_nontemporal_store(
          ov, (f32x4*)(pout + (size_t)rr * S_TOK + kt * 64 + oq * 4));
    }
    asm volatile("" ::: "memory");  // keep next iter's LDS writes after reads
  }

  // ---- pair O combine ----
  if (half == 1) {
#pragma unroll
    for (int mf = 0; mf < 2; ++mf)
#pragma unroll
      for (int nh = 0; nh < 4; ++nh)
#pragma unroll
        for (int r = 0; r < 4; ++r)
          osum[pairi][mf * 16 + g * 4 + r][nh * 16 + l16] = oacc[mf][nh][r];
  }
  __syncthreads();
  if (half == 0) {
#pragma unroll
    for (int mf = 0; mf < 2; ++mf)
#pragma unroll
      for (int nh = 0; nh < 4; ++nh)
#pragma unroll
        for (int r = 0; r < 4; ++r) {
          int row = mf * 16 + g * 4 + r;
          float v = oacc[mf][nh][r] + osum[pairi][row][nh * 16 + l16];
          o_ws[((size_t)b * S_TOK + qrow0 + row) * 1024 + h * HD + nh * 16 +
               l16] = (f16)v;
        }
  }
}

// ---------------------------------------------------------------------------
// Kernel 3: O projection, 128x128 tile (same structure as k_qkv).
// o_ws(f16) @ o_w16 + o_b -> d_out fp32. grid (32, 8).
// ---------------------------------------------------------------------------
__global__ __launch_bounds__(256) void k_oproj(
    const f16* __restrict__ a, const f16* __restrict__ o_w,
    const float* __restrict__ o_b, float* __restrict__ out) {
  __shared__ f16 at[128][72];
  __shared__ f16 bt[128][72];
  const int tid = threadIdx.x;
  const int wave = tid >> 6, lane = tid & 63;
  const int l16 = lane & 15, g = lane >> 4;
  const int wm = wave >> 1, wn = wave & 1;
  const int m0 = blockIdx.x * 128;
  const int n0 = blockIdx.y * 128;

  f32x4 acc[4][4] = {};
  const int arow = tid >> 3, asub = tid & 7;
  const int bkr = (tid >> 4) * 4, bnc = (tid & 15) * 4;

  for (int k0 = 0; k0 < 1024; k0 += 64) {
    f16x8 av[4];
#pragma unroll
    for (int it = 0; it < 4; ++it)
      av[it] = *(const f16x8*)(a + (size_t)(m0 + it * 32 + arow) * 1024 + k0 +
                               asub * 8);
    f16x4 bv[2][4];
#pragma unroll
    for (int it = 0; it < 2; ++it)
#pragma unroll
      for (int kk = 0; kk < 4; ++kk)
        bv[it][kk] = *(const f16x4*)(o_w + (size_t)(k0 + bkr + kk) * 1024 + n0 +
                                     it * 64 + bnc);
    __syncthreads();
#pragma unroll
    for (int it = 0; it < 4; ++it)
      *(f16x8*)&at[it * 32 + arow][asub * 8] = av[it];
#pragma unroll
    for (int it = 0; it < 2; ++it)
#pragma unroll
      for (int i = 0; i < 4; ++i)
        *(f16x4*)&bt[it * 64 + bnc + i][bkr] =
            f16x4{bv[it][0][i], bv[it][1][i], bv[it][2][i], bv[it][3][i]};
    __syncthreads();
#pragma unroll
    for (int ks = 0; ks < 2; ++ks) {
      f16x8 af[4], bf[4];
#pragma unroll
      for (int mi = 0; mi < 4; ++mi)
        af[mi] = *(const f16x8*)&at[wm * 64 + mi * 16 + l16][ks * 32 + g * 8];
#pragma unroll
      for (int ni = 0; ni < 4; ++ni)
        bf[ni] = *(const f16x8*)&bt[wn * 64 + ni * 16 + l16][ks * 32 + g * 8];
#pragma unroll
      for (int mi = 0; mi < 4; ++mi)
#pragma unroll
        for (int ni = 0; ni < 4; ++ni)
          acc[mi][ni] = MFMA_F16(af[mi], bf[ni], acc[mi][ni]);
    }
  }
#pragma unroll
  for (int ni = 0; ni < 4; ++ni) {
    float bsc = o_b[n0 + wn * 64 + ni * 16 + l16];
#pragma unroll
    for (int mi = 0; mi < 4; ++mi)
#pragma unroll
      for (int r = 0; r < 4; ++r) {
        int row = m0 + wm * 64 + mi * 16 + g * 4 + r;
        out[(size_t)row * 1024 + n0 + wn * 64 + ni * 16 + l16] =
            acc[mi][ni][r] + bsc;
      }
  }
}

extern "C" void kernel_launch(void* const* d_in, const int* in_sizes, int n_in,
                              void* d_out, int out_size, void* d_ws,
                              size_t ws_size, hipStream_t stream) {
  (void)in_sizes; (void)n_in; (void)out_size; (void)ws_size;
  const float* x    = (const float*)d_in[0];
  const float* cosp = (const float*)d_in[1];
  const float* sinp = (const float*)d_in[2];
  const float* q_w  = (const float*)d_in[3];
  const float* q_b  = (const float*)d_in[4];
  const float* k_w  = (const float*)d_in[5];
  const float* v_w  = (const float*)d_in[6];
  const float* v_b  = (const float*)d_in[7];
  const float* o_w  = (const float*)d_in[8];
  const float* o_b  = (const float*)d_in[9];

  f16* ws = (f16*)d_ws;
  f16* x16  = ws + OFF_X16;
  f16* qw16 = ws + OFF_QW;
  f16* kw16 = ws + OFF_KW;
  f16* vw16 = ws + OFF_VW;
  f16* ow16 = ws + OFF_OW;
  f16* q_ws = ws + OFF_QS;
  f16* k_ws = ws + OFF_KS;
  f16* v_ws = ws + OFF_VS;
  f16* o_ws = ws + OFF_OS;
  float* out = (float*)d_out;          // attn_output [0, 4194304)
  float* probs = out + 4194304;        // attn_weights

  k_cvt<<<dim3((CVT_TOTAL / 4 + 255) / 256), 256, 0, stream>>>(
      x, q_w, k_w, v_w, o_w, ws);
  k_qkv<<<dim3(32, 12), 256, 0, stream>>>(x16, cosp, sinp, qw16, q_b, kw16,
                                          vw16, v_b, q_ws, k_ws, v_ws);
  k_attn<<<dim3(1024), 256, 0, stream>>>(q_ws, k_ws, v_ws, o_ws, probs);
  k_oproj<<<dim3(32, 8), 256, 0, stream>>>(o_ws, ow16, o_b, out);
}